// Round 1
// 920.694 us; speedup vs baseline: 1.0686x; 1.0686x over previous
//
#include <hip/hip_runtime.h>
#include <cstdint>

typedef unsigned short u16;
typedef unsigned int   u32;

typedef __bf16 bf16_t;
typedef bf16_t bf16x8 __attribute__((ext_vector_type(8)));
typedef float  f32x16 __attribute__((ext_vector_type(16)));

__device__ __forceinline__ float bf2f(u16 v){ u32 u=((u32)v)<<16; float f; __builtin_memcpy(&f,&u,4); return f; }
__device__ __forceinline__ u16 f2bf(float f){ u32 u; __builtin_memcpy(&u,&f,4); u=(u+0x7FFFu+((u>>16)&1u))>>16; return (u16)u; }

// runtime-dtype element fetch -> bf16 bits. fbf=1: buffer is bf16; fbf=0: fp32.
__device__ __forceinline__ u16 cvt(const void* s, long long i, int fbf){
  return fbf ? ((const u16*)s)[i] : f2bf(((const float*)s)[i]);
}

// ---------------------------------------------------------------------------
// dtype detector (robust thresholds). flags[0]=bf16 inputs, flags[1]=int64 idx.
// ---------------------------------------------------------------------------
__global__ void detect_k(const u32* __restrict__ xf, const u32* __restrict__ ix,
                         int* __restrict__ flags){
  __shared__ int c0, c1;
  const int t = threadIdx.x;
  if (t == 0) { c0 = 0; c1 = 0; }
  __syncthreads();
  int a = 0, b = 0;
  for (int i = t; i < 1024; i += 256) {
    u32 w = xf[i];
    int e = (int)((w >> 7) & 0xFFu);
    if (e >= 100 && e <= 140) a++;
  }
  for (int i = t; i < 8192; i += 256) {
    u32 lo = ix[2 * i], hi = ix[2 * i + 1];
    if (lo != 0xFFFFFFFFu && hi != 0u && hi != 0xFFFFFFFFu) b++;
  }
  atomicAdd(&c0, a); atomicAdd(&c1, b);
  __syncthreads();
  if (t == 0) { flags[0] = (c0 >= 768) ? 1 : 0; flags[1] = (c1 == 0) ? 1 : 0; }
}

// ---------------------------------------------------------------------------
// idx transpose+clamp: idxT[k*Npad + p] = clamped int32 row (invalid/pad -> nsrc).
// Removes the int64 branch, all guards, and the 27-element-stride scatter from
// the gconv hot loop (reads become 2-line coalesced per m-frag).
// ---------------------------------------------------------------------------
__global__ void itr_k(const void* __restrict__ idx, int nK, int Nout, int nsrc,
                      int Npad, int* __restrict__ dst, const int* __restrict__ flags){
  const int k = blockIdx.y;
  const int f64 = flags[1];
  for (int p = blockIdx.x * 256 + threadIdx.x; p < Npad; p += gridDim.x * 256) {
    int j = -1;
    if (k < nK && p < Nout) {
      const size_t ii = (size_t)p * nK + k;
      j = f64 ? (int)((const long long*)idx)[ii] : ((const int32_t*)idx)[ii];
    }
    dst[(size_t)k * Npad + p] = (j < 0 || j > nsrc) ? nsrc : j;
  }
}

// ---------------------------------------------------------------------------
// Barrier-free gather-GEMM sparse conv.
//   out[p, coloff+co] = epi( sum_{k,ci} src[idx[p,k], ci] * W[k,ci,co] )
// KEY: the per-lane gathered uint4 IS the mfma_32x32x16_bf16 A-fragment
// (the old LDS round-trip was an identity: lane wrote/read the same address).
// B is pre-arranged by prep_k into coalesced per-chunk fragments
// BTf[(chunk*NF+nf)*64 + lane][8] so each wave loads its own copy (L2-hit).
// -> no LDS, no __syncthreads, no vmcnt(0) drains; 2-stage register pipeline
// with only compile-time indices (no scratch). Waves run fully decoupled.
// C/D: col=lane&31, row=(reg&3)+8*(reg>>2)+4*(lane>>5)  [m74/m101 verified]
// ---------------------------------------------------------------------------
template<int CIN, int NF>
__global__ __launch_bounds__(256) void gconv(
    const u16* __restrict__ src, int nsrc,           // zero row index = nsrc
    const void* __restrict__ idx, int nK,            // legacy path (idxT==null)
    const int* __restrict__ idxT, int Npad,          // transposed clamped idx
    const u16* __restrict__ BTf, int iters,          // iters = nchunk/2
    const u16* __restrict__ bias,
    const u16* __restrict__ resid,                   // may be null; stride=ostride
    void* __restrict__ out, int ostride, int coloff, int Cout,
    int relu, int Nout,
    const int* __restrict__ flags, int out_ext)
{
  const int tid = threadIdx.x;
  const int w = tid >> 6, l = tid & 63;
  const int lm = l & 31, lh = l >> 5;
  const int kloc = lh * 8;
  const int M0 = blockIdx.x * 256;
  const int fbf = flags[0], f64 = flags[1];
  const int32_t* __restrict__ idx32 = (const int32_t*)idx;
  const long long* __restrict__ idx64 = (const long long*)idx;
  const int p0 = M0 + (2 * w) * 32 + lm;   // m-frag 2w
  const int p1 = p0 + 32;                  // m-frag 2w+1

  f32x16 acc[2][NF];
  #pragma unroll
  for (int mm = 0; mm < 2; ++mm)
    #pragma unroll
    for (int nf = 0; nf < NF; ++nf)
      #pragma unroll
      for (int e = 0; e < 16; ++e) acc[mm][nf][e] = 0.f;

  // one pipeline stage = 2 chunks (one 16-wide K slice each)
  auto LD = [&](int it, uint4 (&A)[4], uint4 (&B)[2 * NF]) {
    const int c0 = 2 * it;
    if (CIN >= 32) {
      // both chunks of a stage share one k
      const int k = (CIN == 64) ? (c0 >> 2) : (c0 >> 1);
      int r0, r1;
      if (idxT) {
        r0 = idxT[(size_t)k * Npad + p0];
        r1 = idxT[(size_t)k * Npad + p1];
      } else {
        int j0 = -1, j1 = -1;
        if (k < nK) {
          if (p0 < Nout) { const size_t ii = (size_t)p0 * nK + k; j0 = f64 ? (int)idx64[ii] : idx32[ii]; }
          if (p1 < Nout) { const size_t ii = (size_t)p1 * nK + k; j1 = f64 ? (int)idx64[ii] : idx32[ii]; }
        }
        r0 = (j0 < 0 || j0 > nsrc) ? nsrc : j0;
        r1 = (j1 < 0 || j1 > nsrc) ? nsrc : j1;
      }
      const u16* s0 = src + (size_t)r0 * CIN;
      const u16* s1 = src + (size_t)r1 * CIN;
      #pragma unroll
      for (int s = 0; s < 2; ++s) {
        const int c = c0 + s;
        const int ci = (CIN == 64) ? (((c & 3) << 4) + kloc) : (((c & 1) << 4) + kloc);
        A[s * 2 + 0] = *(const uint4*)(s0 + ci);
        A[s * 2 + 1] = *(const uint4*)(s1 + ci);
      }
    } else { // CIN == 8: k differs per chunk and per lane-half, full row per lane
      #pragma unroll
      for (int s = 0; s < 2; ++s) {
        const int c = c0 + s;
        const int k = c * 2 + lh;
        int r0, r1;
        if (idxT) {
          r0 = idxT[(size_t)k * Npad + p0];
          r1 = idxT[(size_t)k * Npad + p1];
        } else {
          int j0 = -1, j1 = -1;
          if (k < nK) {
            if (p0 < Nout) { const size_t ii = (size_t)p0 * nK + k; j0 = f64 ? (int)idx64[ii] : idx32[ii]; }
            if (p1 < Nout) { const size_t ii = (size_t)p1 * nK + k; j1 = f64 ? (int)idx64[ii] : idx32[ii]; }
          }
          r0 = (j0 < 0 || j0 > nsrc) ? nsrc : j0;
          r1 = (j1 < 0 || j1 > nsrc) ? nsrc : j1;
        }
        A[s * 2 + 0] = *(const uint4*)(src + (size_t)r0 * 8);
        A[s * 2 + 1] = *(const uint4*)(src + (size_t)r1 * 8);
      }
    }
    #pragma unroll
    for (int s = 0; s < 2; ++s)
      #pragma unroll
      for (int nf = 0; nf < NF; ++nf)
        B[s * NF + nf] = *(const uint4*)(BTf + (((size_t)(c0 + s) * NF + nf) * 64 + l) * 8);
  };

  auto MM = [&](const uint4 (&A)[4], const uint4 (&B)[2 * NF]) {
    #pragma unroll
    for (int s = 0; s < 2; ++s) {
      const bf16x8 a0 = __builtin_bit_cast(bf16x8, A[s * 2 + 0]);
      const bf16x8 a1 = __builtin_bit_cast(bf16x8, A[s * 2 + 1]);
      #pragma unroll
      for (int nf = 0; nf < NF; ++nf) {
        const bf16x8 b = __builtin_bit_cast(bf16x8, B[s * NF + nf]);
        acc[0][nf] = __builtin_amdgcn_mfma_f32_32x32x16_bf16(a0, b, acc[0][nf], 0, 0, 0);
        acc[1][nf] = __builtin_amdgcn_mfma_f32_32x32x16_bf16(a1, b, acc[1][nf], 0, 0, 0);
      }
    }
  };

  // 2-deep software pipeline, all register banks statically named
  uint4 A0[4], B0[2 * NF], A1[4], B1[2 * NF];
  LD(0, A0, B0);
  for (int it = 0; it < iters; it += 2) {
    if (it + 1 < iters) LD(it + 1, A1, B1);
    MM(A0, B0);
    if (it + 2 < iters) LD(it + 2, A0, B0);
    if (it + 1 < iters) MM(A1, B1);
  }

  const int fp32out = out_ext && !fbf;
  #pragma unroll
  for (int mm = 0; mm < 2; ++mm) {
    #pragma unroll
    for (int nf = 0; nf < NF; ++nf) {
      const int co = nf * 32 + lm;
      if (co >= Cout) continue;
      const float bv = bf2f(bias[co]);
      #pragma unroll
      for (int r = 0; r < 16; ++r) {
        const int m = (r & 3) + 8 * (r >> 2) + 4 * lh;
        const int p = M0 + (2 * w + mm) * 32 + m;
        if (p >= Nout) continue;
        float v = acc[mm][nf][r] + bv;
        if (resid) v += bf2f(resid[(size_t)p * ostride + coloff + co]);
        if (relu && v < 0.f) v = 0.f;
        const size_t ofs = (size_t)p * ostride + coloff + co;
        if (fp32out) ((float*)out)[ofs] = v;
        else         ((u16*)out)[ofs] = f2bf(v);
      }
    }
  }
}

// ---------------------------------------------------------------------------
// Weight prep: coalesced per-chunk B fragments.
//   BTf[((chunk*NF+nf)*64 + lane)*8 + e] = W'[kk][co],
//   co = nf*32 + (lane&31), kk = chunk*16 + (lane>>5)*8 + e, W'[kk][co] = W[k][ci][co].
// Zero-padded where co>=Cout or kk>=nK*Cin. Flat jobs: plain copy-convert.
// ---------------------------------------------------------------------------
struct PrepJob {
  const void* src; long long eoff; u16* dst;
  int nK, Cin, Cout, COPAD, KKpad, flat, count;
};
struct PrepArgs { PrepJob j[22]; };

__global__ void prep_k(PrepArgs a, const int* __restrict__ flags){
  PrepJob jb = a.j[blockIdx.y];
  const int fbf = flags[0];
  if (jb.flat) {
    for (int t = blockIdx.x * 256 + threadIdx.x; t < jb.count; t += gridDim.x * 256)
      jb.dst[t] = cvt(jb.src, jb.eoff + t, fbf);
    return;
  }
  const int total = jb.COPAD * jb.KKpad;
  const int NFj = jb.COPAD >> 5;            // 1 or 2
  const int kkmax = jb.nK * jb.Cin;
  for (int t = blockIdx.x * 256 + threadIdx.x; t < total; t += gridDim.x * 256) {
    const int e  = t & 7;
    const int lj = (t >> 3) & 63;
    const int cn = t >> 9;                  // chunk*NF + nf
    const int nf = cn & (NFj - 1);
    const int chunk = cn >> (NFj - 1);
    const int co = nf * 32 + (lj & 31);
    const int kk = chunk * 16 + ((lj >> 5) << 3) + e;
    u16 v = 0;
    if (co < jb.Cout && kk < kkmax)
      v = cvt(jb.src, jb.eoff + (long long)kk * jb.Cout + co, fbf);
    jb.dst[t] = v;
  }
}

// xsum = x_feat + f1_ref -> bf16, plus zero row at index N. 8 elems/thread.
__global__ void xsum_k(const void* __restrict__ xa, const void* __restrict__ xb,
                       u16* __restrict__ dst, int n8valid, int n8tot,
                       const int* __restrict__ flags){
  int t = blockIdx.x * 256 + threadIdx.x;
  if (t >= n8tot) return;
  const int fbf = flags[0];
  union { uint4 v; u16 h[8]; } O;
  if (t < n8valid) {
    if (fbf) {
      union { uint4 v; u16 h[8]; } A, B;
      A.v = ((const uint4*)xa)[t];
      B.v = ((const uint4*)xb)[t];
      #pragma unroll
      for (int e = 0; e < 8; ++e) O.h[e] = f2bf(bf2f(A.h[e]) + bf2f(B.h[e]));
    } else {
      const float4* fa = (const float4*)xa;
      const float4* fb = (const float4*)xb;
      float4 a0 = fa[2 * t], a1 = fa[2 * t + 1];
      float4 b0 = fb[2 * t], b1 = fb[2 * t + 1];
      O.h[0] = f2bf(a0.x + b0.x); O.h[1] = f2bf(a0.y + b0.y);
      O.h[2] = f2bf(a0.z + b0.z); O.h[3] = f2bf(a0.w + b0.w);
      O.h[4] = f2bf(a1.x + b1.x); O.h[5] = f2bf(a1.y + b1.y);
      O.h[6] = f2bf(a1.z + b1.z); O.h[7] = f2bf(a1.w + b1.w);
    }
  } else {
    O.v = make_uint4(0, 0, 0, 0);
  }
  ((uint4*)dst)[t] = O.v;
}

// zero the gather "no neighbor" rows (ws re-poisoned every call)
__global__ void zrows_k(u16* out1, int N, u16* od0, u16* od1, u16* h8, u16* t8, int N2){
  int t = threadIdx.x;
  if (t < 64) out1[(size_t)N * 64 + t] = 0;
  if (t < 32) od0[(size_t)N2 * 32 + t] = 0;
  if (t < 32) od1[(size_t)N2 * 32 + t] = 0;
  if (t < 8)  h8[(size_t)N2 * 8 + t] = 0;
  if (t < 8)  t8[(size_t)N2 * 8 + t] = 0;
}

// t8 = relu(od @ W(32x8) + b)   one point/thread. W,b bf16 from ws.
__global__ void t8lin_k(const u16* __restrict__ od, const u16* __restrict__ wsrc,
                        const u16* __restrict__ bsrc, u16* __restrict__ t8, int N2){
  __shared__ u16 wl[256];
  int t = threadIdx.x;
  wl[t] = wsrc[t];
  __syncthreads();
  int p = blockIdx.x * 256 + t;
  if (p >= N2) return;
  union { uint4 v[4]; u16 h[32]; } R;
  const uint4* rp = (const uint4*)(od + (size_t)p * 32);
  R.v[0] = rp[0]; R.v[1] = rp[1]; R.v[2] = rp[2]; R.v[3] = rp[3];
  float acc[8];
  #pragma unroll
  for (int o = 0; o < 8; ++o) acc[o] = bf2f(bsrc[o]);
  #pragma unroll
  for (int c = 0; c < 32; ++c) {
    float f = bf2f(R.h[c]);
    #pragma unroll
    for (int o = 0; o < 8; ++o) acc[o] += f * bf2f(wl[c * 8 + o]);
  }
  union { uint4 v; u16 h[8]; } O;
  #pragma unroll
  for (int o = 0; o < 8; ++o) { float v = acc[o]; if (v < 0.f) v = 0.f; O.h[o] = f2bf(v); }
  ((uint4*)(t8 + (size_t)p * 8))[0] = O.v;
}

// odout[:,16:32] = t2 @ W(8x16) + b + odin[:,16:32]. W,b bf16 from ws.
__global__ void o1lin_k(const u16* __restrict__ t2, const u16* __restrict__ wsrc,
                        const u16* __restrict__ bsrc, const u16* __restrict__ odin,
                        u16* __restrict__ odout, int N2){
  __shared__ u16 wl[128];
  int t = threadIdx.x;
  if (t < 128) wl[t] = wsrc[t];
  __syncthreads();
  int p = blockIdx.x * 256 + t;
  if (p >= N2) return;
  union { uint4 v; u16 h[8]; } R; R.v = ((const uint4*)(t2 + (size_t)p * 8))[0];
  union { uint4 v[2]; u16 h[16]; } Rs;
  const uint4* rp = (const uint4*)(odin + (size_t)p * 32 + 16);
  Rs.v[0] = rp[0]; Rs.v[1] = rp[1];
  float acc[16];
  #pragma unroll
  for (int o = 0; o < 16; ++o) acc[o] = bf2f(bsrc[o]) + bf2f(Rs.h[o]);
  #pragma unroll
  for (int c = 0; c < 8; ++c) {
    float f = bf2f(R.h[c]);
    #pragma unroll
    for (int o = 0; o < 16; ++o) acc[o] += f * bf2f(wl[c * 16 + o]);
  }
  union { uint4 v[2]; u16 h[16]; } O;
  #pragma unroll
  for (int o = 0; o < 16; ++o) O.h[o] = f2bf(acc[o]);
  uint4* op = (uint4*)(odout + (size_t)p * 32 + 16);
  op[0] = O.v[0]; op[1] = O.v[1];
}

extern "C" void kernel_launch(void* const* d_in, const int* in_sizes, int n_in,
                              void* d_out, int out_size, void* d_ws, size_t ws_size,
                              hipStream_t stream) {
  const void* x_feat = d_in[0];
  const void* f1_ref = d_in[1];
  const void* w1   = d_in[2];
  const void* b1   = d_in[3];
  const void* wd   = d_in[4];
  const void* bd   = d_in[5];
  const void* rw00 = d_in[6];
  const void* rb00 = d_in[7];
  const void* rw01 = d_in[8];
  const void* rb01 = d_in[9];
  const void* rw10 = d_in[10];
  const void* rb10 = d_in[11];
  const void* rw11 = d_in[12];
  const void* rb11 = d_in[13];
  const void* rw12 = d_in[14];
  const void* rb12 = d_in[15];
  const void* w4   = d_in[16];
  const void* b4   = d_in[17];
  const void* idx1 = d_in[18];
  const void* idxd = d_in[19];
  const void* idx2 = d_in[20];

  const int N  = in_sizes[0] / 64;
  const int N2 = out_size / 8;

  const int nb1 = (N + 255) / 256;
  const int nb2 = (N2 + 255) / 256;
  const int Npad1 = nb1 * 256;
  const int Npad2 = nb2 * 256;

  // ---- workspace carve (256B aligned) ----
  size_t off = 0;
  auto carve = [&](size_t n) { void* p = (char*)d_ws + off; off = (off + n + 255) & ~(size_t)255; return p; };
  int* flags = (int*)carve(64 * sizeof(int));
  u16* xsum = (u16*)carve((size_t)(N + 1) * 64 * 2);
  u16* out1 = (u16*)carve((size_t)(N + 1) * 64 * 2);
  u16* od0  = (u16*)carve((size_t)(N2 + 1) * 32 * 2);
  u16* od1  = (u16*)carve((size_t)(N2 + 1) * 32 * 2);
  u16* h8   = (u16*)carve((size_t)(N2 + 1) * 8 * 2);
  u16* t8   = (u16*)carve((size_t)(N2 + 1) * 8 * 2);
  u16* t2   = (u16*)carve((size_t)(N2 + 1) * 8 * 2);
  u16* smallw = (u16*)carve((size_t)2048 * 2);
  u16* BT1  = (u16*)carve((size_t)64 * 1728 * 2);
  u16* BTd  = (u16*)carve((size_t)32 * 512 * 2);
  u16* BT00 = (u16*)carve((size_t)3 * 32 * 864 * 2);
  u16* BT01 = (u16*)carve((size_t)3 * 32 * 224 * 2);
  u16* BT11 = (u16*)carve((size_t)3 * 32 * 224 * 2);
  u16* BT4  = (u16*)carve((size_t)32 * 864 * 2);
  const size_t base_off = off;
  // transposed idx maps (optional — legacy path if ws too small)
  int* idx1T = (int*)carve((size_t)27 * Npad1 * 4);
  int* idxdT = (int*)carve((size_t)8  * Npad2 * 4);
  int* idx2T = (int*)carve((size_t)28 * Npad2 * 4);   // k=27 pad row for CIN=8
  const int useT = (off <= ws_size);
  if (base_off > ws_size) return;
  if (!useT) { idx1T = nullptr; idxdT = nullptr; idx2T = nullptr; }

  // smallw layout (bf16 elements)
  u16* cb1   = smallw + 0;     // 64
  u16* cbd   = smallw + 64;    // 32
  u16* crb00 = smallw + 96;    // 24
  u16* crb01 = smallw + 120;   // 48
  u16* crb10 = smallw + 168;   // 24
  u16* crb11 = smallw + 192;   // 24
  u16* crb12 = smallw + 216;   // 48
  u16* cb4   = smallw + 264;   // 8
  u16* crw10 = smallw + 272;   // 768
  u16* crw12 = smallw + 1040;  // 384

  detect_k<<<1, 256, 0, stream>>>((const u32*)x_feat, (const u32*)idx1, flags);

  // ---- weight prep (coalesced fragment layout) ----
  PrepArgs pa;
  pa.j[0]  = { w1, 0, BT1, 27, 64, 64, 64, 1728, 0, 0 };
  pa.j[1]  = { wd, 0, BTd,  8, 64, 32, 32,  512, 0, 0 };
  for (int i = 0; i < 3; ++i) {
    pa.j[2 + i] = { rw00, (long long)i * 6912, BT00 + (size_t)i * 32 * 864, 27, 32,  8, 32, 864, 0, 0 };
    pa.j[5 + i] = { rw01, (long long)i * 3456, BT01 + (size_t)i * 32 * 224, 27,  8, 16, 32, 224, 0, 0 };
    pa.j[8 + i] = { rw11, (long long)i * 1728, BT11 + (size_t)i * 32 * 224, 27,  8,  8, 32, 224, 0, 0 };
  }
  pa.j[11] = { w4, 0, BT4, 27, 32, 8, 32, 864, 0, 0 };
  pa.j[12] = { b1,   0, cb1,   0,0,0,0,0, 1, 64 };
  pa.j[13] = { bd,   0, cbd,   0,0,0,0,0, 1, 32 };
  pa.j[14] = { rb00, 0, crb00, 0,0,0,0,0, 1, 24 };
  pa.j[15] = { rb01, 0, crb01, 0,0,0,0,0, 1, 48 };
  pa.j[16] = { rb10, 0, crb10, 0,0,0,0,0, 1, 24 };
  pa.j[17] = { rb11, 0, crb11, 0,0,0,0,0, 1, 24 };
  pa.j[18] = { rb12, 0, crb12, 0,0,0,0,0, 1, 48 };
  pa.j[19] = { b4,   0, cb4,   0,0,0,0,0, 1, 8 };
  pa.j[20] = { rw10, 0, crw10, 0,0,0,0,0, 1, 768 };
  pa.j[21] = { rw12, 0, crw12, 0,0,0,0,0, 1, 384 };
  prep_k<<<dim3(432, 22), 256, 0, stream>>>(pa, flags);

  if (useT) {
    itr_k<<<dim3(nb1, 27), 256, 0, stream>>>(idx1, 27, N,  N,  Npad1, idx1T, flags);
    itr_k<<<dim3(nb2,  8), 256, 0, stream>>>(idxd,  8, N2, N,  Npad2, idxdT, flags);
    itr_k<<<dim3(nb2, 28), 256, 0, stream>>>(idx2, 27, N2, N2, Npad2, idx2T, flags);
  }

  const int n8valid = N * 8, n8tot = (N + 1) * 8;
  xsum_k<<<(n8tot + 255) / 256, 256, 0, stream>>>(x_feat, f1_ref, xsum, n8valid, n8tot, flags);
  zrows_k<<<1, 256, 0, stream>>>(out1, N, od0, od1, h8, t8, N2);

  // conv1: 27x64->64, relu
  gconv<64, 2><<<nb1, 256, 0, stream>>>(xsum, N, idx1, 27, idx1T, Npad1, BT1, 54,
                                        cb1, nullptr, out1, 64, 0, 64, 1, N, flags, 0);
  // down: 8x64->32, relu
  gconv<64, 1><<<nb2, 256, 0, stream>>>(out1, N, idxd, 8, idxdT, Npad2, BTd, 16,
                                        cbd, nullptr, od0, 32, 0, 32, 1, N2, flags, 0);
  // residual blocks
  for (int i = 0; i < 3; ++i) {
    u16* oin  = (i & 1) ? od1 : od0;
    u16* oout = (i & 1) ? od0 : od1;
    gconv<32, 1><<<nb2, 256, 0, stream>>>(oin, N2, idx2, 27, idx2T, Npad2, BT00 + (size_t)i * 32 * 864, 27,
                                          crb00 + i * 8, nullptr, h8, 8, 0, 8, 1, N2, flags, 0);
    t8lin_k<<<nb2, 256, 0, stream>>>(oin, crw10 + i * 256, crb10 + i * 8, t8, N2);
    gconv<8, 1><<<nb2, 256, 0, stream>>>(h8, N2, idx2, 27, idx2T, Npad2, BT01 + (size_t)i * 32 * 224, 7,
                                         crb01 + i * 16, oin, oout, 32, 0, 16, 0, N2, flags, 0);
    gconv<8, 1><<<nb2, 256, 0, stream>>>(t8, N2, idx2, 27, idx2T, Npad2, BT11 + (size_t)i * 32 * 224, 7,
                                         crb11 + i * 8, nullptr, t2, 8, 0, 8, 1, N2, flags, 0);
    o1lin_k<<<nb2, 256, 0, stream>>>(t2, crw12 + i * 128, crb12 + i * 16, oin, oout, N2);
  }
  // enc4: 27x32->8, no relu -> d_out (dtype per flags[0])
  gconv<32, 1><<<nb2, 256, 0, stream>>>(od1, N2, idx2, 27, idx2T, Npad2, BT4, 27,
                                        cb4, nullptr, d_out, 8, 0, 8, 0, N2, flags, 1);
}

// Round 2
// 817.621 us; speedup vs baseline: 1.2033x; 1.1261x over previous
//
#include <hip/hip_runtime.h>
#include <cstdint>

typedef unsigned short u16;
typedef unsigned int   u32;

typedef __bf16 bf16_t;
typedef bf16_t bf16x8 __attribute__((ext_vector_type(8)));
typedef float  f32x16 __attribute__((ext_vector_type(16)));

__device__ __forceinline__ float bf2f(u16 v){ u32 u=((u32)v)<<16; float f; __builtin_memcpy(&f,&u,4); return f; }
__device__ __forceinline__ u16 f2bf(float f){ u32 u; __builtin_memcpy(&u,&f,4); u=(u+0x7FFFu+((u>>16)&1u))>>16; return (u16)u; }

// runtime-dtype element fetch -> bf16 bits. fbf=1: buffer is bf16; fbf=0: fp32.
__device__ __forceinline__ u16 cvt(const void* s, long long i, int fbf){
  return fbf ? ((const u16*)s)[i] : f2bf(((const float*)s)[i]);
}

// bijective chunked XCD swizzle (m204): hw round-robins blockIdx across 8 XCDs;
// remap so each XCD owns a CONTIGUOUS slab of the grid -> gather working set of
// spatially-adjacent blocks stays inside one XCD's 4MB L2.
__device__ __forceinline__ int xcd_swz(int bo, int nwg){
  const int q = nwg >> 3, r = nwg & 7;
  const int xcd = bo & 7, lin = bo >> 3;
  return (xcd < r ? xcd * (q + 1) : r * (q + 1) + (xcd - r) * q) + lin;
}

// ---------------------------------------------------------------------------
// dtype detector (robust thresholds). flags[0]=bf16 inputs, flags[1]=int64 idx.
// ---------------------------------------------------------------------------
__global__ void detect_k(const u32* __restrict__ xf, const u32* __restrict__ ix,
                         int* __restrict__ flags){
  __shared__ int c0, c1;
  const int t = threadIdx.x;
  if (t == 0) { c0 = 0; c1 = 0; }
  __syncthreads();
  int a = 0, b = 0;
  for (int i = t; i < 1024; i += 256) {
    u32 w = xf[i];
    int e = (int)((w >> 7) & 0xFFu);
    if (e >= 100 && e <= 140) a++;
  }
  for (int i = t; i < 8192; i += 256) {
    u32 lo = ix[2 * i], hi = ix[2 * i + 1];
    if (lo != 0xFFFFFFFFu && hi != 0u && hi != 0xFFFFFFFFu) b++;
  }
  atomicAdd(&c0, a); atomicAdd(&c1, b);
  __syncthreads();
  if (t == 0) { flags[0] = (c0 >= 768) ? 1 : 0; flags[1] = (c1 == 0) ? 1 : 0; }
}

// ---------------------------------------------------------------------------
// idx transpose+clamp, COALESCED both sides (round-1 version column-read the
// row-major idx -> 356MB HBM fetch for a 54MB array).
// One block per 256-point tile: flattened coalesced reads (consecutive lanes
// read consecutive int64s), stage into padded LDS tile, write k-planes
// coalesced. idxT[k*Npad + p] = clamped int32 row (invalid/pad -> nsrc);
// planes k in [nK, nKpad) are all-nsrc (used by CIN=8 chunk padding).
// ---------------------------------------------------------------------------
__global__ __launch_bounds__(256) void itr_k(
    const void* __restrict__ idx, int nK, int nKpad, int Nout, int nsrc,
    int Npad, int* __restrict__ dst, const int* __restrict__ flags){
  __shared__ int tile[28][257];
  const int f64 = flags[1];
  const int t = threadIdx.x;
  const int p0 = blockIdx.x * 256;
  const int32_t*  __restrict__ i32 = (const int32_t*)idx;
  const long long* __restrict__ i64 = (const long long*)idx;
  // strength-reduced (pl,k) walk over flat indices i = t, t+256, ... < 256*nK
  int pl = t / nK;
  int k  = t - pl * nK;
  const int dp = 256 / nK, dk = 256 - dp * nK;
  while (pl < 256) {
    const int p = p0 + pl;
    int j = -1;
    if (p < Nout) {
      const size_t ii = (size_t)p * nK + k;
      j = f64 ? (int)i64[ii] : i32[ii];
    }
    tile[k][pl] = (j < 0 || j > nsrc) ? nsrc : j;
    pl += dp; k += dk;
    if (k >= nK) { k -= nK; pl += 1; }
  }
  __syncthreads();
  for (int kk = 0; kk < nKpad; ++kk) {
    const int v = (kk < nK) ? tile[kk][t] : nsrc;
    dst[(size_t)kk * Npad + p0 + t] = v;   // coalesced 4B writes
  }
}

// ---------------------------------------------------------------------------
// Barrier-free gather-GEMM sparse conv.
//   out[p, coloff+co] = epi( sum_{k,ci} src[idx[p,k], ci] * W[k,ci,co] )
// Per-lane gathered uint4 IS the mfma_32x32x16_bf16 A-fragment; B pre-arranged
// into coalesced per-chunk fragments BTf[(chunk*NF+nf)*64+lane][8].
// No LDS, no barriers; 2-deep register pipeline, static indices only.
// XCD-chunked block swizzle for gather L2 locality.
// C/D: col=lane&31, row=(reg&3)+8*(reg>>2)+4*(lane>>5)  [m74/m101 verified]
// ---------------------------------------------------------------------------
template<int CIN, int NF>
__global__ __launch_bounds__(256) void gconv(
    const u16* __restrict__ src, int nsrc,           // zero row index = nsrc
    const void* __restrict__ idx, int nK,            // legacy path (idxT==null)
    const int* __restrict__ idxT, int Npad,          // transposed clamped idx
    const u16* __restrict__ BTf, int iters,          // iters = nchunk/2
    const u16* __restrict__ bias,
    const u16* __restrict__ resid,                   // may be null; stride=ostride
    void* __restrict__ out, int ostride, int coloff, int Cout,
    int relu, int Nout,
    const int* __restrict__ flags, int out_ext)
{
  const int tid = threadIdx.x;
  const int w = tid >> 6, l = tid & 63;
  const int lm = l & 31, lh = l >> 5;
  const int kloc = lh * 8;
  const int M0 = xcd_swz(blockIdx.x, gridDim.x) * 256;
  const int fbf = flags[0], f64 = flags[1];
  const int32_t* __restrict__ idx32 = (const int32_t*)idx;
  const long long* __restrict__ idx64 = (const long long*)idx;
  const int p0 = M0 + (2 * w) * 32 + lm;   // m-frag 2w
  const int p1 = p0 + 32;                  // m-frag 2w+1

  f32x16 acc[2][NF];
  #pragma unroll
  for (int mm = 0; mm < 2; ++mm)
    #pragma unroll
    for (int nf = 0; nf < NF; ++nf)
      #pragma unroll
      for (int e = 0; e < 16; ++e) acc[mm][nf][e] = 0.f;

  // one pipeline stage = 2 chunks (one 16-wide K slice each)
  auto LD = [&](int it, uint4 (&A)[4], uint4 (&B)[2 * NF]) {
    const int c0 = 2 * it;
    if (CIN >= 32) {
      // both chunks of a stage share one k
      const int k = (CIN == 64) ? (c0 >> 2) : (c0 >> 1);
      int r0, r1;
      if (idxT) {
        r0 = idxT[(size_t)k * Npad + p0];
        r1 = idxT[(size_t)k * Npad + p1];
      } else {
        int j0 = -1, j1 = -1;
        if (k < nK) {
          if (p0 < Nout) { const size_t ii = (size_t)p0 * nK + k; j0 = f64 ? (int)idx64[ii] : idx32[ii]; }
          if (p1 < Nout) { const size_t ii = (size_t)p1 * nK + k; j1 = f64 ? (int)idx64[ii] : idx32[ii]; }
        }
        r0 = (j0 < 0 || j0 > nsrc) ? nsrc : j0;
        r1 = (j1 < 0 || j1 > nsrc) ? nsrc : j1;
      }
      const u16* s0 = src + (size_t)r0 * CIN;
      const u16* s1 = src + (size_t)r1 * CIN;
      #pragma unroll
      for (int s = 0; s < 2; ++s) {
        const int c = c0 + s;
        const int ci = (CIN == 64) ? (((c & 3) << 4) + kloc) : (((c & 1) << 4) + kloc);
        A[s * 2 + 0] = *(const uint4*)(s0 + ci);
        A[s * 2 + 1] = *(const uint4*)(s1 + ci);
      }
    } else { // CIN == 8: k differs per chunk and per lane-half, full row per lane
      #pragma unroll
      for (int s = 0; s < 2; ++s) {
        const int c = c0 + s;
        const int k = c * 2 + lh;
        int r0, r1;
        if (idxT) {
          r0 = idxT[(size_t)k * Npad + p0];
          r1 = idxT[(size_t)k * Npad + p1];
        } else {
          int j0 = -1, j1 = -1;
          if (k < nK) {
            if (p0 < Nout) { const size_t ii = (size_t)p0 * nK + k; j0 = f64 ? (int)idx64[ii] : idx32[ii]; }
            if (p1 < Nout) { const size_t ii = (size_t)p1 * nK + k; j1 = f64 ? (int)idx64[ii] : idx32[ii]; }
          }
          r0 = (j0 < 0 || j0 > nsrc) ? nsrc : j0;
          r1 = (j1 < 0 || j1 > nsrc) ? nsrc : j1;
        }
        A[s * 2 + 0] = *(const uint4*)(src + (size_t)r0 * 8);
        A[s * 2 + 1] = *(const uint4*)(src + (size_t)r1 * 8);
      }
    }
    #pragma unroll
    for (int s = 0; s < 2; ++s)
      #pragma unroll
      for (int nf = 0; nf < NF; ++nf)
        B[s * NF + nf] = *(const uint4*)(BTf + (((size_t)(c0 + s) * NF + nf) * 64 + l) * 8);
  };

  auto MM = [&](const uint4 (&A)[4], const uint4 (&B)[2 * NF]) {
    #pragma unroll
    for (int s = 0; s < 2; ++s) {
      const bf16x8 a0 = __builtin_bit_cast(bf16x8, A[s * 2 + 0]);
      const bf16x8 a1 = __builtin_bit_cast(bf16x8, A[s * 2 + 1]);
      #pragma unroll
      for (int nf = 0; nf < NF; ++nf) {
        const bf16x8 b = __builtin_bit_cast(bf16x8, B[s * NF + nf]);
        acc[0][nf] = __builtin_amdgcn_mfma_f32_32x32x16_bf16(a0, b, acc[0][nf], 0, 0, 0);
        acc[1][nf] = __builtin_amdgcn_mfma_f32_32x32x16_bf16(a1, b, acc[1][nf], 0, 0, 0);
      }
    }
  };

  // 2-deep software pipeline, all register banks statically named
  uint4 A0[4], B0[2 * NF], A1[4], B1[2 * NF];
  LD(0, A0, B0);
  for (int it = 0; it < iters; it += 2) {
    if (it + 1 < iters) LD(it + 1, A1, B1);
    MM(A0, B0);
    if (it + 2 < iters) LD(it + 2, A0, B0);
    if (it + 1 < iters) MM(A1, B1);
  }

  const int fp32out = out_ext && !fbf;
  #pragma unroll
  for (int mm = 0; mm < 2; ++mm) {
    #pragma unroll
    for (int nf = 0; nf < NF; ++nf) {
      const int co = nf * 32 + lm;
      if (co >= Cout) continue;
      const float bv = bf2f(bias[co]);
      #pragma unroll
      for (int r = 0; r < 16; ++r) {
        const int m = (r & 3) + 8 * (r >> 2) + 4 * lh;
        const int p = M0 + (2 * w + mm) * 32 + m;
        if (p >= Nout) continue;
        float v = acc[mm][nf][r] + bv;
        if (resid) v += bf2f(resid[(size_t)p * ostride + coloff + co]);
        if (relu && v < 0.f) v = 0.f;
        const size_t ofs = (size_t)p * ostride + coloff + co;
        if (fp32out) ((float*)out)[ofs] = v;
        else         ((u16*)out)[ofs] = f2bf(v);
      }
    }
  }
}

// ---------------------------------------------------------------------------
// Weight prep: coalesced per-chunk B fragments.
//   BTf[((chunk*NF+nf)*64 + lane)*8 + e] = W'[kk][co],
//   co = nf*32 + (lane&31), kk = chunk*16 + (lane>>5)*8 + e, W'[kk][co] = W[k][ci][co].
// Zero-padded where co>=Cout or kk>=nK*Cin. Flat jobs: plain copy-convert.
// ---------------------------------------------------------------------------
struct PrepJob {
  const void* src; long long eoff; u16* dst;
  int nK, Cin, Cout, COPAD, KKpad, flat, count;
};
struct PrepArgs { PrepJob j[22]; };

__global__ void prep_k(PrepArgs a, const int* __restrict__ flags){
  PrepJob jb = a.j[blockIdx.y];
  const int fbf = flags[0];
  if (jb.flat) {
    for (int t = blockIdx.x * 256 + threadIdx.x; t < jb.count; t += gridDim.x * 256)
      jb.dst[t] = cvt(jb.src, jb.eoff + t, fbf);
    return;
  }
  const int total = jb.COPAD * jb.KKpad;
  const int NFj = jb.COPAD >> 5;            // 1 or 2
  const int kkmax = jb.nK * jb.Cin;
  for (int t = blockIdx.x * 256 + threadIdx.x; t < total; t += gridDim.x * 256) {
    const int e  = t & 7;
    const int lj = (t >> 3) & 63;
    const int cn = t >> 9;                  // chunk*NF + nf
    const int nf = cn & (NFj - 1);
    const int chunk = cn >> (NFj - 1);
    const int co = nf * 32 + (lj & 31);
    const int kk = chunk * 16 + ((lj >> 5) << 3) + e;
    u16 v = 0;
    if (co < jb.Cout && kk < kkmax)
      v = cvt(jb.src, jb.eoff + (long long)kk * jb.Cout + co, fbf);
    jb.dst[t] = v;
  }
}

// xsum = x_feat + f1_ref -> bf16, plus zero row at index N. 8 elems/thread.
__global__ void xsum_k(const void* __restrict__ xa, const void* __restrict__ xb,
                       u16* __restrict__ dst, int n8valid, int n8tot,
                       const int* __restrict__ flags){
  int t = blockIdx.x * 256 + threadIdx.x;
  if (t >= n8tot) return;
  const int fbf = flags[0];
  union { uint4 v; u16 h[8]; } O;
  if (t < n8valid) {
    if (fbf) {
      union { uint4 v; u16 h[8]; } A, B;
      A.v = ((const uint4*)xa)[t];
      B.v = ((const uint4*)xb)[t];
      #pragma unroll
      for (int e = 0; e < 8; ++e) O.h[e] = f2bf(bf2f(A.h[e]) + bf2f(B.h[e]));
    } else {
      const float4* fa = (const float4*)xa;
      const float4* fb = (const float4*)xb;
      float4 a0 = fa[2 * t], a1 = fa[2 * t + 1];
      float4 b0 = fb[2 * t], b1 = fb[2 * t + 1];
      O.h[0] = f2bf(a0.x + b0.x); O.h[1] = f2bf(a0.y + b0.y);
      O.h[2] = f2bf(a0.z + b0.z); O.h[3] = f2bf(a0.w + b0.w);
      O.h[4] = f2bf(a1.x + b1.x); O.h[5] = f2bf(a1.y + b1.y);
      O.h[6] = f2bf(a1.z + b1.z); O.h[7] = f2bf(a1.w + b1.w);
    }
  } else {
    O.v = make_uint4(0, 0, 0, 0);
  }
  ((uint4*)dst)[t] = O.v;
}

// zero the gather "no neighbor" rows (ws re-poisoned every call)
__global__ void zrows_k(u16* out1, int N, u16* od0, u16* od1, u16* h8, u16* t8, int N2){
  int t = threadIdx.x;
  if (t < 64) out1[(size_t)N * 64 + t] = 0;
  if (t < 32) od0[(size_t)N2 * 32 + t] = 0;
  if (t < 32) od1[(size_t)N2 * 32 + t] = 0;
  if (t < 8)  h8[(size_t)N2 * 8 + t] = 0;
  if (t < 8)  t8[(size_t)N2 * 8 + t] = 0;
}

// t8 = relu(od @ W(32x8) + b)   one point/thread. W,b bf16 from ws.
__global__ void t8lin_k(const u16* __restrict__ od, const u16* __restrict__ wsrc,
                        const u16* __restrict__ bsrc, u16* __restrict__ t8, int N2){
  __shared__ u16 wl[256];
  int t = threadIdx.x;
  wl[t] = wsrc[t];
  __syncthreads();
  int p = blockIdx.x * 256 + t;
  if (p >= N2) return;
  union { uint4 v[4]; u16 h[32]; } R;
  const uint4* rp = (const uint4*)(od + (size_t)p * 32);
  R.v[0] = rp[0]; R.v[1] = rp[1]; R.v[2] = rp[2]; R.v[3] = rp[3];
  float acc[8];
  #pragma unroll
  for (int o = 0; o < 8; ++o) acc[o] = bf2f(bsrc[o]);
  #pragma unroll
  for (int c = 0; c < 32; ++c) {
    float f = bf2f(R.h[c]);
    #pragma unroll
    for (int o = 0; o < 8; ++o) acc[o] += f * bf2f(wl[c * 8 + o]);
  }
  union { uint4 v; u16 h[8]; } O;
  #pragma unroll
  for (int o = 0; o < 8; ++o) { float v = acc[o]; if (v < 0.f) v = 0.f; O.h[o] = f2bf(v); }
  ((uint4*)(t8 + (size_t)p * 8))[0] = O.v;
}

// odout[:,16:32] = t2 @ W(8x16) + b + odin[:,16:32]. W,b bf16 from ws.
__global__ void o1lin_k(const u16* __restrict__ t2, const u16* __restrict__ wsrc,
                        const u16* __restrict__ bsrc, const u16* __restrict__ odin,
                        u16* __restrict__ odout, int N2){
  __shared__ u16 wl[128];
  int t = threadIdx.x;
  if (t < 128) wl[t] = wsrc[t];
  __syncthreads();
  int p = blockIdx.x * 256 + t;
  if (p >= N2) return;
  union { uint4 v; u16 h[8]; } R; R.v = ((const uint4*)(t2 + (size_t)p * 8))[0];
  union { uint4 v[2]; u16 h[16]; } Rs;
  const uint4* rp = (const uint4*)(odin + (size_t)p * 32 + 16);
  Rs.v[0] = rp[0]; Rs.v[1] = rp[1];
  float acc[16];
  #pragma unroll
  for (int o = 0; o < 16; ++o) acc[o] = bf2f(bsrc[o]) + bf2f(Rs.h[o]);
  #pragma unroll
  for (int c = 0; c < 8; ++c) {
    float f = bf2f(R.h[c]);
    #pragma unroll
    for (int o = 0; o < 16; ++o) acc[o] += f * bf2f(wl[c * 16 + o]);
  }
  union { uint4 v[2]; u16 h[16]; } O;
  #pragma unroll
  for (int o = 0; o < 16; ++o) O.h[o] = f2bf(acc[o]);
  uint4* op = (uint4*)(odout + (size_t)p * 32 + 16);
  op[0] = O.v[0]; op[1] = O.v[1];
}

extern "C" void kernel_launch(void* const* d_in, const int* in_sizes, int n_in,
                              void* d_out, int out_size, void* d_ws, size_t ws_size,
                              hipStream_t stream) {
  const void* x_feat = d_in[0];
  const void* f1_ref = d_in[1];
  const void* w1   = d_in[2];
  const void* b1   = d_in[3];
  const void* wd   = d_in[4];
  const void* bd   = d_in[5];
  const void* rw00 = d_in[6];
  const void* rb00 = d_in[7];
  const void* rw01 = d_in[8];
  const void* rb01 = d_in[9];
  const void* rw10 = d_in[10];
  const void* rb10 = d_in[11];
  const void* rw11 = d_in[12];
  const void* rb11 = d_in[13];
  const void* rw12 = d_in[14];
  const void* rb12 = d_in[15];
  const void* w4   = d_in[16];
  const void* b4   = d_in[17];
  const void* idx1 = d_in[18];
  const void* idxd = d_in[19];
  const void* idx2 = d_in[20];

  const int N  = in_sizes[0] / 64;
  const int N2 = out_size / 8;

  const int nb1 = (N + 255) / 256;
  const int nb2 = (N2 + 255) / 256;
  const int Npad1 = nb1 * 256;
  const int Npad2 = nb2 * 256;

  // ---- workspace carve (256B aligned) ----
  size_t off = 0;
  auto carve = [&](size_t n) { void* p = (char*)d_ws + off; off = (off + n + 255) & ~(size_t)255; return p; };
  int* flags = (int*)carve(64 * sizeof(int));
  u16* xsum = (u16*)carve((size_t)(N + 1) * 64 * 2);
  u16* out1 = (u16*)carve((size_t)(N + 1) * 64 * 2);
  u16* od0  = (u16*)carve((size_t)(N2 + 1) * 32 * 2);
  u16* od1  = (u16*)carve((size_t)(N2 + 1) * 32 * 2);
  u16* h8   = (u16*)carve((size_t)(N2 + 1) * 8 * 2);
  u16* t8   = (u16*)carve((size_t)(N2 + 1) * 8 * 2);
  u16* t2   = (u16*)carve((size_t)(N2 + 1) * 8 * 2);
  u16* smallw = (u16*)carve((size_t)2048 * 2);
  u16* BT1  = (u16*)carve((size_t)64 * 1728 * 2);
  u16* BTd  = (u16*)carve((size_t)32 * 512 * 2);
  u16* BT00 = (u16*)carve((size_t)3 * 32 * 864 * 2);
  u16* BT01 = (u16*)carve((size_t)3 * 32 * 224 * 2);
  u16* BT11 = (u16*)carve((size_t)3 * 32 * 224 * 2);
  u16* BT4  = (u16*)carve((size_t)32 * 864 * 2);
  const size_t base_off = off;
  // transposed idx maps (optional — legacy path if ws too small)
  int* idx1T = (int*)carve((size_t)27 * Npad1 * 4);
  int* idxdT = (int*)carve((size_t)8  * Npad2 * 4);
  int* idx2T = (int*)carve((size_t)28 * Npad2 * 4);   // k=27 pad row for CIN=8
  const int useT = (off <= ws_size);
  if (base_off > ws_size) return;
  if (!useT) { idx1T = nullptr; idxdT = nullptr; idx2T = nullptr; }

  // smallw layout (bf16 elements)
  u16* cb1   = smallw + 0;     // 64
  u16* cbd   = smallw + 64;    // 32
  u16* crb00 = smallw + 96;    // 24
  u16* crb01 = smallw + 120;   // 48
  u16* crb10 = smallw + 168;   // 24
  u16* crb11 = smallw + 192;   // 24
  u16* crb12 = smallw + 216;   // 48
  u16* cb4   = smallw + 264;   // 8
  u16* crw10 = smallw + 272;   // 768
  u16* crw12 = smallw + 1040;  // 384

  detect_k<<<1, 256, 0, stream>>>((const u32*)x_feat, (const u32*)idx1, flags);

  // ---- weight prep (coalesced fragment layout) ----
  PrepArgs pa;
  pa.j[0]  = { w1, 0, BT1, 27, 64, 64, 64, 1728, 0, 0 };
  pa.j[1]  = { wd, 0, BTd,  8, 64, 32, 32,  512, 0, 0 };
  for (int i = 0; i < 3; ++i) {
    pa.j[2 + i] = { rw00, (long long)i * 6912, BT00 + (size_t)i * 32 * 864, 27, 32,  8, 32, 864, 0, 0 };
    pa.j[5 + i] = { rw01, (long long)i * 3456, BT01 + (size_t)i * 32 * 224, 27,  8, 16, 32, 224, 0, 0 };
    pa.j[8 + i] = { rw11, (long long)i * 1728, BT11 + (size_t)i * 32 * 224, 27,  8,  8, 32, 224, 0, 0 };
  }
  pa.j[11] = { w4, 0, BT4, 27, 32, 8, 32, 864, 0, 0 };
  pa.j[12] = { b1,   0, cb1,   0,0,0,0,0, 1, 64 };
  pa.j[13] = { bd,   0, cbd,   0,0,0,0,0, 1, 32 };
  pa.j[14] = { rb00, 0, crb00, 0,0,0,0,0, 1, 24 };
  pa.j[15] = { rb01, 0, crb01, 0,0,0,0,0, 1, 48 };
  pa.j[16] = { rb10, 0, crb10, 0,0,0,0,0, 1, 24 };
  pa.j[17] = { rb11, 0, crb11, 0,0,0,0,0, 1, 24 };
  pa.j[18] = { rb12, 0, crb12, 0,0,0,0,0, 1, 48 };
  pa.j[19] = { b4,   0, cb4,   0,0,0,0,0, 1, 8 };
  pa.j[20] = { rw10, 0, crw10, 0,0,0,0,0, 1, 768 };
  pa.j[21] = { rw12, 0, crw12, 0,0,0,0,0, 1, 384 };
  prep_k<<<dim3(432, 22), 256, 0, stream>>>(pa, flags);

  if (useT) {
    itr_k<<<nb1, 256, 0, stream>>>(idx1, 27, 27, N,  N,  Npad1, idx1T, flags);
    itr_k<<<nb2, 256, 0, stream>>>(idxd,  8,  8, N2, N,  Npad2, idxdT, flags);
    itr_k<<<nb2, 256, 0, stream>>>(idx2, 27, 28, N2, N2, Npad2, idx2T, flags);
  }

  const int n8valid = N * 8, n8tot = (N + 1) * 8;
  xsum_k<<<(n8tot + 255) / 256, 256, 0, stream>>>(x_feat, f1_ref, xsum, n8valid, n8tot, flags);
  zrows_k<<<1, 256, 0, stream>>>(out1, N, od0, od1, h8, t8, N2);

  // conv1: 27x64->64, relu
  gconv<64, 2><<<nb1, 256, 0, stream>>>(xsum, N, idx1, 27, idx1T, Npad1, BT1, 54,
                                        cb1, nullptr, out1, 64, 0, 64, 1, N, flags, 0);
  // down: 8x64->32, relu
  gconv<64, 1><<<nb2, 256, 0, stream>>>(out1, N, idxd, 8, idxdT, Npad2, BTd, 16,
                                        cbd, nullptr, od0, 32, 0, 32, 1, N2, flags, 0);
  // residual blocks
  for (int i = 0; i < 3; ++i) {
    u16* oin  = (i & 1) ? od1 : od0;
    u16* oout = (i & 1) ? od0 : od1;
    gconv<32, 1><<<nb2, 256, 0, stream>>>(oin, N2, idx2, 27, idx2T, Npad2, BT00 + (size_t)i * 32 * 864, 27,
                                          crb00 + i * 8, nullptr, h8, 8, 0, 8, 1, N2, flags, 0);
    t8lin_k<<<nb2, 256, 0, stream>>>(oin, crw10 + i * 256, crb10 + i * 8, t8, N2);
    gconv<8, 1><<<nb2, 256, 0, stream>>>(h8, N2, idx2, 27, idx2T, Npad2, BT01 + (size_t)i * 32 * 224, 7,
                                         crb01 + i * 16, oin, oout, 32, 0, 16, 0, N2, flags, 0);
    gconv<8, 1><<<nb2, 256, 0, stream>>>(t8, N2, idx2, 27, idx2T, Npad2, BT11 + (size_t)i * 32 * 224, 7,
                                         crb11 + i * 8, nullptr, t2, 8, 0, 8, 1, N2, flags, 0);
    o1lin_k<<<nb2, 256, 0, stream>>>(t2, crw12 + i * 128, crb12 + i * 16, oin, oout, N2);
  }
  // enc4: 27x32->8, no relu -> d_out (dtype per flags[0])
  gconv<32, 1><<<nb2, 256, 0, stream>>>(od1, N2, idx2, 27, idx2T, Npad2, BT4, 27,
                                        cb4, nullptr, d_out, 8, 0, 8, 0, N2, flags, 1);
}